// Round 7
// baseline (110.588 us; speedup 1.0000x reference)
//
#include <hip/hip_runtime.h>

#define BATCH 128
#define DIM 256
#define NTH 6
#define NF 1536          // NUM_FACTS
#define NODES 1023
#define NPAD 1024
#define OD 8
#define INV_TAU (1.0f/0.7f)
#define CLIP_EPS 1e-6f

// GEMM tiling
#define BN 16            // nodes per tile
#define NTILES 64        // 64 * 16 = 1024 >= 1023
#define KC 192           // k per chunk
#define KSPLIT 8         // 8 * 192 = 1536
#define GP 200           // LDS g pitch in halves (400 B row)
#define NBLK (NTILES * KSPLIT)   // 512 blocks; 2/CU guaranteed -> co-resident

typedef _Float16 half_t;
typedef __attribute__((ext_vector_type(8))) _Float16 half8;
typedef __attribute__((ext_vector_type(4))) _Float16 half4;
typedef __attribute__((ext_vector_type(4))) float f32x4;

// ws layout (bytes)
#define OFF_PART 0                                // partial [8][128][1024] f16 = 2 MiB
#define OFF_CS   (2*1024*1024)                    // cS [8][2][1024] f32 = 64 KiB
#define OFF_FT   (2*1024*1024 + 65536)            // fT [192][128][8] f16 = 384 KiB
#define OFF_BAR  (2*1024*1024 + 65536 + 393216)   // 2 barrier counters

__device__ __forceinline__ void gridbar(unsigned* ctr) {
    __syncthreads();
    if (threadIdx.x == 0) {
        __hip_atomic_fetch_add(ctr, 1u, __ATOMIC_RELEASE, __HIP_MEMORY_SCOPE_AGENT);
        while (__hip_atomic_load(ctr, __ATOMIC_ACQUIRE, __HIP_MEMORY_SCOPE_AGENT) < (unsigned)NBLK)
            __builtin_amdgcn_s_sleep(1);
    }
    __syncthreads();
}

__global__ __launch_bounds__(256, 2) void k_all(const float* __restrict__ x,
                                                const float* __restrict__ th,
                                                const float* __restrict__ sl,
                                                const float* __restrict__ logits,
                                                const float* __restrict__ LV,
                                                half_t* __restrict__ fT,
                                                half_t* __restrict__ partial,
                                                float* __restrict__ cS,
                                                unsigned* __restrict__ bar,
                                                float* __restrict__ out) {
    __shared__ union SMem {
        half_t gs[BN * GP];                                        // phase B: 6.4 KiB
        struct { float tl[NPAD]; float A[512 * OD]; float B[256 * OD]; } tr;  // phase C: 28 KiB
    } sm;
    const int tid = threadIdx.x;
    const int blk = blockIdx.x;

    // ================= phase A: facts -> fT [k8][b][8] fp16 =================
    if (tid < 48) {
        const int cell = blk * 48 + tid;                  // 512*48 = 24576 cells
        const int b = cell & 127;
        const int k8 = cell >> 7;                         // 0..191
        const int kbase = k8 * 8;
        const int d0 = kbase / NTH;                       // rem = kbase%6 is even -> spans <= 2 features
        const int jsw = NTH - (kbase - NTH * d0);
        const float x0 = x[b * DIM + d0];
        const float x1 = x[b * DIM + d0 + 1];
        float4 tA = *(const float4*)&th[kbase];
        float4 tB = *(const float4*)&th[kbase + 4];
        float4 sA = *(const float4*)&sl[kbase];
        float4 sB = *(const float4*)&sl[kbase + 4];
        float t8[8] = {tA.x, tA.y, tA.z, tA.w, tB.x, tB.y, tB.z, tB.w};
        float s8[8] = {sA.x, sA.y, sA.z, sA.w, sB.x, sB.y, sB.z, sB.w};
        union { half_t h[8]; uint4 u; } p;
        #pragma unroll
        for (int j = 0; j < 8; ++j) {
            float xv = (j < jsw) ? x0 : x1;
            float z = (xv - t8[j]) * s8[j];
            p.h[j] = (half_t)(1.0f / (1.0f + __expf(-z)));
        }
        *(uint4*)&fT[(size_t)cell * 8] = p.u;
    }
    gridbar(&bar[0]);

    // ================= phase B: split-K MFMA GEMM =================
    {
        const int tile = blk >> 3;          // 0..63
        const int chunk = blk & 7;          // 0..7
        const int n0 = tile * BN;
        const int k0 = chunk * KC;

        // stage g = e1 - e2 (fp16) into LDS; per-chunk c = sum e2, S = sum(e1+e2)
        const int r = tid >> 4;             // 0..15 node row
        const int j = tid & 15;             // 0..15 lane in row
        const int n = n0 + r;
        float cpart = 0.f, spart = 0.f;
        if (n < NODES) {
            const float* row = logits + (size_t)n * (2 * NF) + k0;
            #pragma unroll
            for (int i = 0; i < 6; ++i) {
                int kp = j * 2 + 32 * i;
                float2 a1 = *(const float2*)&row[kp];
                float2 a2 = *(const float2*)&row[kp + NF];
                float e10 = __expf(a1.x * INV_TAU), e11 = __expf(a1.y * INV_TAU);
                float e20 = __expf(a2.x * INV_TAU), e21 = __expf(a2.y * INV_TAU);
                union { half_t h[2]; unsigned int u; } p;
                p.h[0] = (half_t)(e10 - e20); p.h[1] = (half_t)(e11 - e21);
                *(unsigned int*)&sm.gs[r * GP + kp] = p.u;
                cpart += e20 + e21;
                spart += e10 + e11 + e20 + e21;
            }
        } else {
            #pragma unroll
            for (int i = 0; i < 6; ++i)
                *(unsigned int*)&sm.gs[r * GP + j * 2 + 32 * i] = 0u;
        }
        cpart += __shfl_xor(cpart, 1); cpart += __shfl_xor(cpart, 2);
        cpart += __shfl_xor(cpart, 4); cpart += __shfl_xor(cpart, 8);
        spart += __shfl_xor(spart, 1); spart += __shfl_xor(spart, 2);
        spart += __shfl_xor(spart, 4); spart += __shfl_xor(spart, 8);
        if (j == 0 && n < NODES) {
            cS[(size_t)chunk * (2 * NPAD) + n] = cpart;
            cS[(size_t)chunk * (2 * NPAD) + NPAD + n] = spart;
        }
        __syncthreads();

        // MFMA: out[n 16][b 128]; 4 waves x 2 b-tiles of 16
        const int wave = tid >> 6;
        const int lane = tid & 63;
        const int bcol = lane & 15;
        const int kq = lane >> 4;           // 0..3
        const int b0 = wave * 32;
        // B fragments: coalesced 256B segments from fT (L2/L3-warm)
        const half8* fp = (const half8*)(fT + ((size_t)((k0 >> 3) + kq) * BATCH + b0 + bcol) * 8);
        half8 bva[6], bvb[6];
        #pragma unroll
        for (int s = 0; s < 6; ++s) {
            bva[s] = fp[(size_t)s * 512];        // +4 k8-groups per step
            bvb[s] = fp[(size_t)s * 512 + 16];   // b-tile +16
        }
        f32x4 acc0 = {0.f, 0.f, 0.f, 0.f};
        f32x4 acc1 = {0.f, 0.f, 0.f, 0.f};
        const half_t* ga = sm.gs + bcol * GP + kq * 8;
        #pragma unroll
        for (int s = 0; s < 6; ++s) {
            half8 av = *(const half8*)(ga + s * 32);
            acc0 = __builtin_amdgcn_mfma_f32_16x16x32_f16(av, bva[s], acc0, 0, 0, 0);
            acc1 = __builtin_amdgcn_mfma_f32_16x16x32_f16(av, bvb[s], acc1, 0, 0, 0);
        }
        // D layout: col(b)=lane&15, row(n)=(lane>>4)*4+reg ; store fp16 partials
        half4 h0, h1;
        #pragma unroll
        for (int i = 0; i < 4; ++i) { h0[i] = (half_t)acc0[i]; h1[i] = (half_t)acc1[i]; }
        half_t* p0 = partial + (size_t)chunk * (BATCH * NPAD) + (size_t)(b0 + bcol) * NPAD + n0 + kq * 4;
        *(half4*)p0 = h0;
        *(half4*)(p0 + (size_t)16 * NPAD) = h1;
    }
    gridbar(&bar[1]);

    // ================= phase C: split-K reduce + tree (blocks 0..127) =================
    if (blk >= BATCH) return;
    {
        const int b = blk;
        // t for 4 nodes per thread
        const int n4 = tid * 4;
        float s0 = 0.f, s1 = 0.f, s2 = 0.f, s3 = 0.f;
        float c0 = 0.f, c1 = 0.f, c2 = 0.f, c3 = 0.f;
        float S0 = 0.f, S1 = 0.f, S2 = 0.f, S3 = 0.f;
        #pragma unroll
        for (int ch = 0; ch < KSPLIT; ++ch) {
            half4 p = *(const half4*)&partial[(size_t)ch * (BATCH * NPAD) + (size_t)b * NPAD + n4];
            float4 cc = *(const float4*)&cS[(size_t)ch * (2 * NPAD) + n4];
            float4 SS = *(const float4*)&cS[(size_t)ch * (2 * NPAD) + NPAD + n4];
            s0 += (float)p[0]; s1 += (float)p[1]; s2 += (float)p[2]; s3 += (float)p[3];
            c0 += cc.x; c1 += cc.y; c2 += cc.z; c3 += cc.w;
            S0 += SS.x; S1 += SS.y; S2 += SS.z; S3 += SS.w;
        }
        sm.tr.tl[n4 + 0] = fminf(fmaxf((s0 + c0) / S0, CLIP_EPS), 1.0f - CLIP_EPS);
        sm.tr.tl[n4 + 1] = fminf(fmaxf((s1 + c1) / S1, CLIP_EPS), 1.0f - CLIP_EPS);
        sm.tr.tl[n4 + 2] = fminf(fmaxf((s2 + c2) / S2, CLIP_EPS), 1.0f - CLIP_EPS);
        sm.tr.tl[n4 + 3] = fminf(fmaxf((s3 + c3) / S3, CLIP_EPS), 1.0f - CLIP_EPS);
        __syncthreads();

        // depth-9 internal nodes (511..1022): combine leaf_value children
        for (int w = tid; w < 512 * OD; w += 256) {
            int i = w >> 3, o = w & 7;
            float tv = sm.tr.tl[511 + i];
            sm.tr.A[w] = (1.0f - tv) * LV[i * 16 + o] + tv * LV[i * 16 + 8 + o];
        }
        __syncthreads();

        float* cur = sm.tr.A;
        float* nxt = sm.tr.B;
        for (int lev = 8; lev >= 0; --lev) {
            int cnt = 1 << lev;
            int base = cnt - 1;
            for (int w = tid; w < cnt * OD; w += 256) {
                int i = w >> 3, o = w & 7;
                float tv = sm.tr.tl[base + i];
                nxt[w] = (1.0f - tv) * cur[i * 16 + o] + tv * cur[i * 16 + 8 + o];
            }
            __syncthreads();
            float* tmp = cur; cur = nxt; nxt = tmp;
        }
        if (tid < OD) out[b * OD + tid] = cur[tid];
    }
}

extern "C" void kernel_launch(void* const* d_in, const int* in_sizes, int n_in,
                              void* d_out, int out_size, void* d_ws, size_t ws_size,
                              hipStream_t stream) {
    const float* x      = (const float*)d_in[0];
    const float* th     = (const float*)d_in[1];
    const float* sl     = (const float*)d_in[2];
    const float* logits = (const float*)d_in[3];
    const float* LV     = (const float*)d_in[4];
    float* out = (float*)d_out;
    char* ws = (char*)d_ws;
    half_t* partial = (half_t*)(ws + OFF_PART);
    float* cS       = (float*)(ws + OFF_CS);
    half_t* fT      = (half_t*)(ws + OFF_FT);
    unsigned* bar   = (unsigned*)(ws + OFF_BAR);

    hipMemsetAsync(bar, 0, 8, stream);
    k_all<<<NBLK, 256, 0, stream>>>(x, th, sl, logits, LV, fT, partial, cS, bar, out);
}

// Round 8
// 55.373 us; speedup vs baseline: 1.9972x; 1.9972x over previous
//
#include <hip/hip_runtime.h>

#define BATCH 128
#define DIM 256
#define NTH 6
#define NF 1536          // NUM_FACTS
#define NODES 1023
#define NPAD 1024
#define OD 8
#define INV_TAU (1.0f/0.7f)
#define CLIP_EPS 1e-6f

// GEMM tiling (identical to round-4 best: 20.9us)
#define BN 16            // nodes per tile
#define NTILES 64        // 64 * 16 = 1024 >= 1023
#define KC 192           // k per chunk
#define KSPLIT 8         // 8 * 192 = 1536
#define GP 200           // LDS g pitch in halves

typedef _Float16 half_t;
typedef __attribute__((ext_vector_type(8))) _Float16 half8;
typedef __attribute__((ext_vector_type(4))) float f32x4;

// ws layout (bytes)
#define OFF_PART 0                         // partial [8][128][1024] f32 = 4 MiB
#define OFF_CS   (4*1024*1024)             // cS [8][2][1024] f32 = 64 KiB
#define OFF_FT   (4*1024*1024 + 65536)     // fT [192][128][8] f16 = 384 KiB

__global__ __launch_bounds__(256) void k_facts(const float* __restrict__ x,
                                               const float* __restrict__ th,
                                               const float* __restrict__ sl,
                                               half_t* __restrict__ fT) {
    const int idx = blockIdx.x * 256 + threadIdx.x;   // (k8*128 + b), 24576 total
    const int b = idx & 127;
    const int k8 = idx >> 7;                          // 0..191
    const int kbase = k8 * 8;
    const int d0 = kbase / NTH;
    const int jsw = NTH - (kbase - NTH * d0);
    const float x0 = x[b * DIM + d0];
    const float x1 = x[b * DIM + d0 + 1];
    float4 tA = *(const float4*)&th[kbase];
    float4 tB = *(const float4*)&th[kbase + 4];
    float4 sA = *(const float4*)&sl[kbase];
    float4 sB = *(const float4*)&sl[kbase + 4];
    float t8[8] = {tA.x, tA.y, tA.z, tA.w, tB.x, tB.y, tB.z, tB.w};
    float s8[8] = {sA.x, sA.y, sA.z, sA.w, sB.x, sB.y, sB.z, sB.w};
    union { half_t h[8]; uint4 u; } p;
    #pragma unroll
    for (int j = 0; j < 8; ++j) {
        float xv = (j < jsw) ? x0 : x1;
        float z = (xv - t8[j]) * s8[j];
        p.h[j] = (half_t)(1.0f / (1.0f + __expf(-z)));
    }
    *(uint4*)&fT[(size_t)idx * 8] = p.u;
}

__global__ __launch_bounds__(256) void k_gemm(const float* __restrict__ logits,
                                              const half_t* __restrict__ fT,
                                              float* __restrict__ partial,
                                              float* __restrict__ cS) {
    __shared__ __align__(16) half_t gs[BN * GP];
    const int tid = threadIdx.x;
    const int tile = blockIdx.x >> 3;       // 0..63
    const int chunk = blockIdx.x & 7;       // 0..7
    const int n0 = tile * BN;
    const int k0 = chunk * KC;

    // prefetch B fragments (fT, coalesced 256B segments) into registers
    const int wave = tid >> 6;
    const int lane = tid & 63;
    const int bcol = lane & 15;
    const int kq = lane >> 4;               // 0..3
    const int b0 = wave * 32;
    const half8* fp = (const half8*)(fT + ((size_t)((k0 >> 3) + kq) * BATCH + b0 + bcol) * 8);
    half8 bva[6], bvb[6];
    #pragma unroll
    for (int s = 0; s < 6; ++s) {
        bva[s] = fp[(size_t)s * 512];
        bvb[s] = fp[(size_t)s * 512 + 16];
    }

    // stage g = e1 - e2 (fp16) into LDS; per-chunk c = sum e2, S = sum(e1+e2)
    const int r = tid >> 4;                 // 0..15 node row
    const int j = tid & 15;                 // 0..15 lane in row
    const int n = n0 + r;
    float cpart = 0.f, spart = 0.f;
    if (n < NODES) {
        const float* row = logits + (size_t)n * (2 * NF) + k0;
        #pragma unroll
        for (int i = 0; i < 6; ++i) {
            int kp = j * 2 + 32 * i;
            float2 a1 = *(const float2*)&row[kp];
            float2 a2 = *(const float2*)&row[kp + NF];
            float e10 = __expf(a1.x * INV_TAU), e11 = __expf(a1.y * INV_TAU);
            float e20 = __expf(a2.x * INV_TAU), e21 = __expf(a2.y * INV_TAU);
            union { half_t h[2]; unsigned int u; } p;
            p.h[0] = (half_t)(e10 - e20); p.h[1] = (half_t)(e11 - e21);
            *(unsigned int*)&gs[r * GP + kp] = p.u;
            cpart += e20 + e21;
            spart += e10 + e11 + e20 + e21;
        }
    } else {
        #pragma unroll
        for (int i = 0; i < 6; ++i)
            *(unsigned int*)&gs[r * GP + j * 2 + 32 * i] = 0u;
    }
    cpart += __shfl_xor(cpart, 1); cpart += __shfl_xor(cpart, 2);
    cpart += __shfl_xor(cpart, 4); cpart += __shfl_xor(cpart, 8);
    spart += __shfl_xor(spart, 1); spart += __shfl_xor(spart, 2);
    spart += __shfl_xor(spart, 4); spart += __shfl_xor(spart, 8);
    if (j == 0 && n < NODES) {
        cS[(size_t)chunk * (2 * NPAD) + n] = cpart;
        cS[(size_t)chunk * (2 * NPAD) + NPAD + n] = spart;
    }
    __syncthreads();

    // MFMA: out[n 16][b 128]; 4 waves x 2 b-tiles of 16
    f32x4 acc0 = {0.f, 0.f, 0.f, 0.f};
    f32x4 acc1 = {0.f, 0.f, 0.f, 0.f};
    const half_t* ga = gs + bcol * GP + kq * 8;
    #pragma unroll
    for (int s = 0; s < 6; ++s) {
        half8 av = *(const half8*)(ga + s * 32);
        acc0 = __builtin_amdgcn_mfma_f32_16x16x32_f16(av, bva[s], acc0, 0, 0, 0);
        acc1 = __builtin_amdgcn_mfma_f32_16x16x32_f16(av, bvb[s], acc1, 0, 0, 0);
    }

    float* p0 = partial + (size_t)chunk * (BATCH * NPAD) + (size_t)(b0 + bcol) * NPAD + n0 + kq * 4;
    *(f32x4*)p0 = acc0;
    *(f32x4*)(p0 + (size_t)16 * NPAD) = acc1;
}

__global__ __launch_bounds__(256) void k_tree(const float* __restrict__ partial,
                                              const float* __restrict__ cS,
                                              const float* __restrict__ LV,
                                              float* __restrict__ out) {
    __shared__ float tl[NPAD];
    __shared__ float Abuf[512 * OD];
    __shared__ float Bbuf[256 * OD];
    const int b = blockIdx.x;
    const int tid = threadIdx.x;

    {
        const int n4 = tid * 4;
        float4 s = make_float4(0.f, 0.f, 0.f, 0.f);
        float4 c = make_float4(0.f, 0.f, 0.f, 0.f);
        float4 S = make_float4(0.f, 0.f, 0.f, 0.f);
        #pragma unroll
        for (int ch = 0; ch < KSPLIT; ++ch) {
            float4 p = *(const float4*)&partial[(size_t)ch * (BATCH * NPAD) + (size_t)b * NPAD + n4];
            float4 cc = *(const float4*)&cS[(size_t)ch * (2 * NPAD) + n4];
            float4 SS = *(const float4*)&cS[(size_t)ch * (2 * NPAD) + NPAD + n4];
            s.x += p.x; s.y += p.y; s.z += p.z; s.w += p.w;
            c.x += cc.x; c.y += cc.y; c.z += cc.z; c.w += cc.w;
            S.x += SS.x; S.y += SS.y; S.z += SS.z; S.w += SS.w;
        }
        float4 tv;
        tv.x = fminf(fmaxf((s.x + c.x) / S.x, CLIP_EPS), 1.0f - CLIP_EPS);
        tv.y = fminf(fmaxf((s.y + c.y) / S.y, CLIP_EPS), 1.0f - CLIP_EPS);
        tv.z = fminf(fmaxf((s.z + c.z) / S.z, CLIP_EPS), 1.0f - CLIP_EPS);
        tv.w = fminf(fmaxf((s.w + c.w) / S.w, CLIP_EPS), 1.0f - CLIP_EPS);
        *(float4*)&tl[n4] = tv;
    }
    __syncthreads();

    for (int w = tid; w < 512 * OD; w += 256) {
        int i = w >> 3, o = w & 7;
        float tv = tl[511 + i];
        Abuf[w] = (1.0f - tv) * LV[i * 16 + o] + tv * LV[i * 16 + 8 + o];
    }
    __syncthreads();

    float* cur = Abuf;
    float* nxt = Bbuf;
    for (int lev = 8; lev >= 0; --lev) {
        int cnt = 1 << lev;
        int base = cnt - 1;
        for (int w = tid; w < cnt * OD; w += 256) {
            int i = w >> 3, o = w & 7;
            float tv = tl[base + i];
            nxt[w] = (1.0f - tv) * cur[i * 16 + o] + tv * cur[i * 16 + 8 + o];
        }
        __syncthreads();
        float* tmp = cur; cur = nxt; nxt = tmp;
    }
    if (tid < OD) out[b * OD + tid] = cur[tid];
}

extern "C" void kernel_launch(void* const* d_in, const int* in_sizes, int n_in,
                              void* d_out, int out_size, void* d_ws, size_t ws_size,
                              hipStream_t stream) {
    const float* x      = (const float*)d_in[0];
    const float* th     = (const float*)d_in[1];
    const float* sl     = (const float*)d_in[2];
    const float* logits = (const float*)d_in[3];
    const float* LV     = (const float*)d_in[4];
    float* out = (float*)d_out;
    char* ws = (char*)d_ws;
    float* partial = (float*)(ws + OFF_PART);
    float* cS      = (float*)(ws + OFF_CS);
    half_t* fT     = (half_t*)(ws + OFF_FT);

    k_facts<<<96, 256, 0, stream>>>(x, th, sl, fT);
    // CALIBRATION: k_gemm is idempotent (pure stores). Launch 10x to measure
    // T_gemm from the total: total = R + 10*T_gemm, round-4 anchor: 20.9 = R + T_gemm.
    for (int rep = 0; rep < 10; ++rep)
        k_gemm<<<NTILES * KSPLIT, 256, 0, stream>>>(logits, fT, partial, cS);
    k_tree<<<BATCH, 256, 0, stream>>>(partial, cS, LV, out);
}

// Round 9
// 22.604 us; speedup vs baseline: 4.8924x; 2.4497x over previous
//
#include <hip/hip_runtime.h>

#define BATCH 128
#define DIM 256
#define NTH 6
#define NF 1536          // NUM_FACTS
#define NODES 1023
#define NPAD 1024
#define OD 8
#define INV_TAU (1.0f/0.7f)
#define CLIP_EPS 1e-6f

// GEMM tiling
#define BN 16            // nodes per tile
#define NTILES 64        // 64 * 16 = 1024 >= 1023
#define KC 192           // k per chunk (= 24 k8-groups)
#define KSPLIT 8         // 8 * 192 = 1536
#define GP 200           // LDS g pitch in halves

typedef _Float16 half_t;
typedef __attribute__((ext_vector_type(8))) _Float16 half8;
typedef __attribute__((ext_vector_type(4))) _Float16 half4;
typedef __attribute__((ext_vector_type(4))) float f32x4;

// ws layout (bytes)
#define OFF_PART 0                         // partial [8][128][1024] f16 = 2 MiB
#define OFF_CS   (2*1024*1024)             // cS [8][2][1024] f32 = 64 KiB

__global__ __launch_bounds__(256) void k_gemm(const float* __restrict__ x,
                                              const float* __restrict__ th,
                                              const float* __restrict__ sl,
                                              const float* __restrict__ logits,
                                              half_t* __restrict__ partial,
                                              float* __restrict__ cS) {
    __shared__ __align__(16) half_t fs[24 * BATCH * 8];   // 48 KiB facts [k8][b][8]
    __shared__ __align__(16) half_t gs[BN * GP];          // 6.4 KiB g = e1-e2
    const int tid = threadIdx.x;
    const int tile = blockIdx.x >> 3;       // 0..63
    const int chunk = blockIdx.x & 7;       // 0..7
    const int n0 = tile * BN;
    const int k0 = chunk * KC;

    // ---- issue logits loads into registers FIRST (HBM latency hides under facts VALU)
    const int r = tid >> 4;                 // 0..15 node row
    const int j = tid & 15;                 // 0..15 lane in row
    const int n = n0 + r;
    float2 a1[6], a2[6];
    if (n < NODES) {
        const float* row = logits + (size_t)n * (2 * NF) + k0;
        #pragma unroll
        for (int i = 0; i < 6; ++i) {
            int kp = j * 2 + 32 * i;
            a1[i] = *(const float2*)&row[kp];
            a2[i] = *(const float2*)&row[kp + NF];
        }
    }

    // ---- facts for this chunk: 3072 cells (k8 local 0..23, b 0..127), 12 per thread
    #pragma unroll
    for (int i = 0; i < 12; ++i) {
        const int cell = i * 256 + tid;
        const int k8l = cell >> 7;                    // 0..23
        const int b = cell & 127;
        const int kbase = (chunk * 24 + k8l) * 8;
        const int d0 = kbase / NTH;                   // kbase%6 even -> spans <= 2 features
        const int jsw = NTH - (kbase - NTH * d0);
        const float x0 = x[b * DIM + d0];
        const float x1 = x[b * DIM + d0 + 1];
        float4 tA = *(const float4*)&th[kbase];
        float4 tB = *(const float4*)&th[kbase + 4];
        float4 sA = *(const float4*)&sl[kbase];
        float4 sB = *(const float4*)&sl[kbase + 4];
        float t8[8] = {tA.x, tA.y, tA.z, tA.w, tB.x, tB.y, tB.z, tB.w};
        float s8[8] = {sA.x, sA.y, sA.z, sA.w, sB.x, sB.y, sB.z, sB.w};
        union { half_t h[8]; uint4 u; } p;
        #pragma unroll
        for (int q = 0; q < 8; ++q) {
            float xv = (q < jsw) ? x0 : x1;
            float z = (xv - t8[q]) * s8[q];
            p.h[q] = (half_t)(1.0f / (1.0f + __expf(-z)));
        }
        *(uint4*)&fs[(size_t)cell * 8] = p.u;
    }

    // ---- g = e1 - e2 (fp16) into LDS; per-chunk c = sum e2, S = sum(e1+e2)
    float cpart = 0.f, spart = 0.f;
    if (n < NODES) {
        #pragma unroll
        for (int i = 0; i < 6; ++i) {
            int kp = j * 2 + 32 * i;
            float e10 = __expf(a1[i].x * INV_TAU), e11 = __expf(a1[i].y * INV_TAU);
            float e20 = __expf(a2[i].x * INV_TAU), e21 = __expf(a2[i].y * INV_TAU);
            union { half_t h[2]; unsigned int u; } p;
            p.h[0] = (half_t)(e10 - e20); p.h[1] = (half_t)(e11 - e21);
            *(unsigned int*)&gs[r * GP + kp] = p.u;
            cpart += e20 + e21;
            spart += e10 + e11 + e20 + e21;
        }
    } else {
        #pragma unroll
        for (int i = 0; i < 6; ++i)
            *(unsigned int*)&gs[r * GP + j * 2 + 32 * i] = 0u;
    }
    cpart += __shfl_xor(cpart, 1); cpart += __shfl_xor(cpart, 2);
    cpart += __shfl_xor(cpart, 4); cpart += __shfl_xor(cpart, 8);
    spart += __shfl_xor(spart, 1); spart += __shfl_xor(spart, 2);
    spart += __shfl_xor(spart, 4); spart += __shfl_xor(spart, 8);
    if (j == 0 && n < NODES) {
        cS[(size_t)chunk * (2 * NPAD) + n] = cpart;
        cS[(size_t)chunk * (2 * NPAD) + NPAD + n] = spart;
    }
    __syncthreads();

    // ---- MFMA: out[n 16][b 128]; 4 waves x 2 b-tiles of 16
    const int wave = tid >> 6;
    const int lane = tid & 63;
    const int bcol = lane & 15;
    const int kq = lane >> 4;               // 0..3
    const int b0 = wave * 32;
    f32x4 acc0 = {0.f, 0.f, 0.f, 0.f};
    f32x4 acc1 = {0.f, 0.f, 0.f, 0.f};
    const half_t* ga = gs + bcol * GP + kq * 8;
    #pragma unroll
    for (int s = 0; s < 6; ++s) {
        // local k8 for this fragment = s*4 + kq  (k = kq*8 + s*32 .. +8)
        const half_t* fb = fs + ((size_t)((s * 4 + kq) * BATCH) + b0 + bcol) * 8;
        half8 av  = *(const half8*)(ga + s * 32);
        half8 bv0 = *(const half8*)fb;
        half8 bv1 = *(const half8*)(fb + 16 * 8);
        acc0 = __builtin_amdgcn_mfma_f32_16x16x32_f16(av, bv0, acc0, 0, 0, 0);
        acc1 = __builtin_amdgcn_mfma_f32_16x16x32_f16(av, bv1, acc1, 0, 0, 0);
    }

    // D layout: col(b)=lane&15, row(n)=(lane>>4)*4+reg ; fp16 partials
    half4 h0, h1;
    #pragma unroll
    for (int i = 0; i < 4; ++i) { h0[i] = (half_t)acc0[i]; h1[i] = (half_t)acc1[i]; }
    half_t* p0 = partial + (size_t)chunk * (BATCH * NPAD) + (size_t)(b0 + bcol) * NPAD + n0 + kq * 4;
    *(half4*)p0 = h0;
    *(half4*)(p0 + (size_t)16 * NPAD) = h1;
}

__global__ __launch_bounds__(256) void k_tree(const half_t* __restrict__ partial,
                                              const float* __restrict__ cS,
                                              const float* __restrict__ LV,
                                              float* __restrict__ out) {
    __shared__ float tl[NPAD];
    __shared__ float Abuf[512 * OD];
    __shared__ float Bbuf[256 * OD];
    const int b = blockIdx.x;
    const int tid = threadIdx.x;

    {
        const int n4 = tid * 4;
        float s0 = 0.f, s1 = 0.f, s2 = 0.f, s3 = 0.f;
        float c0 = 0.f, c1 = 0.f, c2 = 0.f, c3 = 0.f;
        float S0 = 0.f, S1 = 0.f, S2 = 0.f, S3 = 0.f;
        #pragma unroll
        for (int ch = 0; ch < KSPLIT; ++ch) {
            half4 p = *(const half4*)&partial[(size_t)ch * (BATCH * NPAD) + (size_t)b * NPAD + n4];
            float4 cc = *(const float4*)&cS[(size_t)ch * (2 * NPAD) + n4];
            float4 SS = *(const float4*)&cS[(size_t)ch * (2 * NPAD) + NPAD + n4];
            s0 += (float)p[0]; s1 += (float)p[1]; s2 += (float)p[2]; s3 += (float)p[3];
            c0 += cc.x; c1 += cc.y; c2 += cc.z; c3 += cc.w;
            S0 += SS.x; S1 += SS.y; S2 += SS.z; S3 += SS.w;
        }
        tl[n4 + 0] = fminf(fmaxf((s0 + c0) / S0, CLIP_EPS), 1.0f - CLIP_EPS);
        tl[n4 + 1] = fminf(fmaxf((s1 + c1) / S1, CLIP_EPS), 1.0f - CLIP_EPS);
        tl[n4 + 2] = fminf(fmaxf((s2 + c2) / S2, CLIP_EPS), 1.0f - CLIP_EPS);
        tl[n4 + 3] = fminf(fmaxf((s3 + c3) / S3, CLIP_EPS), 1.0f - CLIP_EPS);
    }
    __syncthreads();

    for (int w = tid; w < 512 * OD; w += 256) {
        int i = w >> 3, o = w & 7;
        float tv = tl[511 + i];
        Abuf[w] = (1.0f - tv) * LV[i * 16 + o] + tv * LV[i * 16 + 8 + o];
    }
    __syncthreads();

    float* cur = Abuf;
    float* nxt = Bbuf;
    for (int lev = 8; lev >= 0; --lev) {
        int cnt = 1 << lev;
        int base = cnt - 1;
        for (int w = tid; w < cnt * OD; w += 256) {
            int i = w >> 3, o = w & 7;
            float tv = tl[base + i];
            nxt[w] = (1.0f - tv) * cur[i * 16 + o] + tv * cur[i * 16 + 8 + o];
        }
        __syncthreads();
        float* tmp = cur; cur = nxt; nxt = tmp;
    }
    if (tid < OD) out[b * OD + tid] = cur[tid];
}

extern "C" void kernel_launch(void* const* d_in, const int* in_sizes, int n_in,
                              void* d_out, int out_size, void* d_ws, size_t ws_size,
                              hipStream_t stream) {
    const float* x      = (const float*)d_in[0];
    const float* th     = (const float*)d_in[1];
    const float* sl     = (const float*)d_in[2];
    const float* logits = (const float*)d_in[3];
    const float* LV     = (const float*)d_in[4];
    float* out = (float*)d_out;
    char* ws = (char*)d_ws;
    half_t* partial = (half_t*)(ws + OFF_PART);
    float* cS       = (float*)(ws + OFF_CS);

    k_gemm<<<NTILES * KSPLIT, 256, 0, stream>>>(x, th, sl, logits, partial, cS);
    k_tree<<<BATCH, 256, 0, stream>>>(partial, cS, LV, out);
}